// Round 5
// baseline (666.752 us; speedup 1.0000x reference)
//
#include <hip/hip_runtime.h>
#include <math.h>

// SpectralNorm: sigma = max(1, s_max(w2d)/2); w = w_bar/sigma; conv3x3 pad1 + bias.
// x: [32,32,256,256] f32, w_bar: [32,32,3,3] f32, bias: [32] f32, out same as x.
//
// R5: conv = implicit GEMM on f16 matrix cores, 2-term split on W only
// (x_f16*whi + x_f16*wlo): f16's 11-bit mantissa leaves only x-rounding error
// (~1e-3 max, absmax is sigma-dominated at 0.03125). vs R3/R4:
//  - 2/3 the MFMA work of bf16 3-term, single x-plane in LDS (half the staging)
//  - 16x64 tile, 64-col stores (R4's 32-col tiles caused 1.4x write amplification)
//  - weights read from global/L2, not LDS (R3's unpadded weight LDS was 8M conflicts)

typedef __attribute__((ext_vector_type(8))) _Float16 f16x8;  // MFMA A/B operand
typedef __attribute__((ext_vector_type(16))) float f32x16;   // MFMA C/D (16 VGPR)
typedef __attribute__((ext_vector_type(8))) unsigned short u16x8;

__device__ __forceinline__ unsigned short f16bits(float v) {
  _Float16 h = (_Float16)v;
  return __builtin_bit_cast(unsigned short, h);
}

// ---------------- prep: sigma via G = W W^T, squaring + power iter ----------------
// Output: f16 hi/lo split of w_bar/sigma in [q][k][c] layout (q = 3*dy+dx).
__global__ __launch_bounds__(1024) void sn_prep_kernel(
    const float* __restrict__ w_bar,      // [32][288] row-major (k major)
    unsigned short* __restrict__ w_out)   // [2][9][32][32]: hi plane then lo plane
{
  __shared__ __align__(16) float sw[9216];    // [k][t]
  __shared__ __align__(16) float swT[9216];   // [t][k]
  __shared__ float G0[1024];
  __shared__ float Gpp[2048];
  __shared__ float vvec[32];
  __shared__ float svec[32];
  __shared__ float scal[2];
  const int tid = threadIdx.x;

  for (int i = tid; i < 9216; i += 1024) {
    float v = w_bar[i];
    sw[i] = v;
    int k = i / 288;
    int t = i - k * 288;
    swT[t * 32 + k] = v;
  }
  __syncthreads();

  // G[i][j] = dot(row i, row j) over 288; one element per thread, 2-chain ILP
  {
    const int i = tid >> 5, j = tid & 31;
    const float* ri = &sw[i * 288];
    float s0 = 0.f, s1 = 0.f;
    for (int t = 0; t < 288; t += 8) {
      float4 a = *(const float4*)(ri + t);
      float4 b = *(const float4*)(ri + t + 4);
      s0 = fmaf(a.x, swT[(t + 0) * 32 + j], s0);
      s0 = fmaf(a.y, swT[(t + 1) * 32 + j], s0);
      s0 = fmaf(a.z, swT[(t + 2) * 32 + j], s0);
      s0 = fmaf(a.w, swT[(t + 3) * 32 + j], s0);
      s1 = fmaf(b.x, swT[(t + 4) * 32 + j], s1);
      s1 = fmaf(b.y, swT[(t + 5) * 32 + j], s1);
      s1 = fmaf(b.z, swT[(t + 6) * 32 + j], s1);
      s1 = fmaf(b.w, swT[(t + 7) * 32 + j], s1);
    }
    G0[tid] = s0 + s1;
  }

  // 6 normalized squarings -> direction of G^64
  const float* src = G0;
  for (int sq = 0; sq < 6; ++sq) {
    float* dst = &Gpp[(sq & 1) * 1024];
    __syncthreads();
    {
      const int i = tid >> 5, j = tid & 31;
      float s0 = 0.f, s1 = 0.f;
#pragma unroll
      for (int t = 0; t < 32; t += 2) {
        s0 = fmaf(src[i * 32 + t], src[t * 32 + j], s0);
        s1 = fmaf(src[i * 32 + t + 1], src[(t + 1) * 32 + j], s1);
      }
      dst[tid] = s0 + s1;
    }
    __syncthreads();
    float s0 = dst[0];
    float inv = (s0 > 0.f) ? (1.f / s0) : 1.f;
    __syncthreads();
    dst[tid] *= inv;
    src = dst;
  }

  if (tid < 32) vvec[tid] = 1.f;
  __syncthreads();
  for (int it = 0; it < 4; ++it) {
    if (tid < 32) {
      float s = 0.f;
#pragma unroll
      for (int j = 0; j < 32; ++j) s = fmaf(src[tid * 32 + j], vvec[j], s);
      svec[tid] = s;
    }
    __syncthreads();
    if (tid == 0) {
      float n2 = 0.f;
      for (int j = 0; j < 32; ++j) n2 += svec[j] * svec[j];
      scal[0] = (n2 > 0.f) ? rsqrtf(n2) : 0.f;
    }
    __syncthreads();
    if (tid < 32) vvec[tid] = svec[tid] * scal[0];
    __syncthreads();
  }

  if (tid < 32) {
    float s = 0.f;
#pragma unroll
    for (int j = 0; j < 32; ++j) s = fmaf(G0[tid * 32 + j], vvec[j], s);
    svec[tid] = s * vvec[tid];
  }
  __syncthreads();
  if (tid == 0) {
    float lam = 0.f;
    for (int j = 0; j < 32; ++j) lam += svec[j];
    lam = fmaxf(lam, 0.f);
    float sigma = fmaxf(1.f, 0.5f * sqrtf(lam));
    scal[1] = 1.f / sigma;
  }
  __syncthreads();
  float inv_sigma = scal[1];
  // emit f16 hi/lo in [q][k][c] layout (e = q*1024 + k*32 + c)
  for (int e = tid; e < 9216; e += 1024) {
    int q = e >> 10;
    int rem = e & 1023;
    int k = rem >> 5;
    int c = rem & 31;
    float w = sw[k * 288 + c * 9 + q] * inv_sigma;
    _Float16 hb = (_Float16)w;
    float lo = w - (float)hb;
    w_out[e] = __builtin_bit_cast(unsigned short, hb);
    w_out[9216 + e] = f16bits(lo);
  }
}

// ---------------- conv: implicit GEMM on v_mfma_f32_32x32x16_f16 ----------------
// Block: 512 thr (8 waves), tile = 16 out-rows x 64 cols x 32 k, one n.
// GEMM K-dim slices = 8 channels x 2 taps; taps padded 9->10 (q=9: A-frag zeroed
// in-register; its B-read aliases q=8's address so no garbage enters the MFMA).
// A-frag: from GLOBAL (L2-resident): lane holds Whi/Wlo[k=l31][c0+j] at q=2p+half.
// B-frag: lane holds x_f16[c0+j][r_o+dy(q)][col+dx(q)] (channel-innermost LDS -> b128)
// D: col=lane&31, row k = 4*(lane>>5) + (reg&3) + 8*(reg>>2)   [measured m74/m101]
__global__ __launch_bounds__(512, 4) void sn_conv_mfma(
    const float* __restrict__ x, const unsigned short* __restrict__ wsp,
    const float* __restrict__ bias, float* __restrict__ out)
{
  __shared__ __align__(16) unsigned short sx[9792];  // [18 r][68 colpad][8 c] f16 bits

  const int tid  = threadIdx.x;
  const int lane = tid & 63;
  const int wv   = tid >> 6;          // 0..7
  const int l31  = lane & 31;
  const int half = lane >> 5;
  const int n  = blockIdx.z;
  const int y0 = blockIdx.y * 16;
  const int x0 = blockIdx.x * 64;

  // bias folded into accumulator init; k = kb + (reg&3) + 8*(reg>>2)
  const int kb = 4 * half;
  const float4 b0 = *(const float4*)&bias[kb];
  const float4 b1 = *(const float4*)&bias[kb + 8];
  const float4 b2 = *(const float4*)&bias[kb + 16];
  const float4 b3 = *(const float4*)&bias[kb + 24];
  f32x16 acc0;
  acc0[0] = b0.x; acc0[1] = b0.y; acc0[2]  = b0.z; acc0[3]  = b0.w;
  acc0[4] = b1.x; acc0[5] = b1.y; acc0[6]  = b1.z; acc0[7]  = b1.w;
  acc0[8] = b2.x; acc0[9] = b2.y; acc0[10] = b2.z; acc0[11] = b2.w;
  acc0[12] = b3.x; acc0[13] = b3.y; acc0[14] = b3.z; acc0[15] = b3.w;
  f32x16 acc1 = acc0, acc2 = acc0, acc3 = acc0;

  // per-lane B offsets per K-slice p: q_b = min(2p+half, 8)
  int offB[5];
#pragma unroll
  for (int p = 0; p < 5; ++p) {
    int q = 2 * p + half; if (q > 8) q = 8;
    int dy = q / 3;
    int dx = q - 3 * dy;
    offB[p] = (dy * 68 + dx) * 8;
  }

  // B-frag LDS bases for the 4 spatial tiles of this wave
  const int db[4] = {
    ((wv * 2 + 0) * 68 +  0 + l31) * 8,
    ((wv * 2 + 0) * 68 + 32 + l31) * 8,
    ((wv * 2 + 1) * 68 +  0 + l31) * 8,
    ((wv * 2 + 1) * 68 + 32 + l31) * 8,
  };

  const float* xn = x + (size_t)n * 32 * 65536;

  for (int cs = 0; cs < 4; ++cs) {
    const int c0 = cs * 8;
    __syncthreads();  // previous iteration's B-reads done before overwrite

    // stage 8 channels + halo: fp32 -> f16, layout [r][col][c] (c innermost)
    for (int idx = tid; idx < 18 * 66; idx += 512) {
      int r   = idx / 66;
      int col = idx - r * 66;
      int gy = y0 - 1 + r;
      int gx = x0 - 1 + col;
      bool ok = ((unsigned)gy < 256u) && ((unsigned)gx < 256u);
      const float* px = xn + (size_t)c0 * 65536 + gy * 256 + gx;
      u16x8 hv;
#pragma unroll
      for (int cl = 0; cl < 8; ++cl) {
        float v = ok ? px[(size_t)cl * 65536] : 0.f;
        hv[cl] = f16bits(v);
      }
      *(u16x8*)&sx[(r * 68 + col) * 8] = hv;
    }
    __syncthreads();

    // per K-slice: A hi/lo from global (L2), 4 B-frags from LDS, 8 MFMA
#pragma unroll
    for (int p = 0; p < 5; ++p) {
      int qa = 2 * p + half;
      int qc = qa > 8 ? 8 : qa;
      int off = qc * 1024 + l31 * 32 + c0;
      u16x8 h = *(const u16x8*)&wsp[off];
      u16x8 l = *(const u16x8*)&wsp[9216 + off];
      if (qa == 9) {
        h = (u16x8)(0);
        l = (u16x8)(0);
      }
      f16x8 aH = __builtin_bit_cast(f16x8, h);
      f16x8 aL = __builtin_bit_cast(f16x8, l);
      f16x8 bf0 = __builtin_bit_cast(f16x8, *(const u16x8*)&sx[db[0] + offB[p]]);
      f16x8 bf1 = __builtin_bit_cast(f16x8, *(const u16x8*)&sx[db[1] + offB[p]]);
      f16x8 bf2 = __builtin_bit_cast(f16x8, *(const u16x8*)&sx[db[2] + offB[p]]);
      f16x8 bf3 = __builtin_bit_cast(f16x8, *(const u16x8*)&sx[db[3] + offB[p]]);
      acc0 = __builtin_amdgcn_mfma_f32_32x32x16_f16(aH, bf0, acc0, 0, 0, 0);
      acc1 = __builtin_amdgcn_mfma_f32_32x32x16_f16(aH, bf1, acc1, 0, 0, 0);
      acc2 = __builtin_amdgcn_mfma_f32_32x32x16_f16(aH, bf2, acc2, 0, 0, 0);
      acc3 = __builtin_amdgcn_mfma_f32_32x32x16_f16(aH, bf3, acc3, 0, 0, 0);
      acc0 = __builtin_amdgcn_mfma_f32_32x32x16_f16(aL, bf0, acc0, 0, 0, 0);
      acc1 = __builtin_amdgcn_mfma_f32_32x32x16_f16(aL, bf1, acc1, 0, 0, 0);
      acc2 = __builtin_amdgcn_mfma_f32_32x32x16_f16(aL, bf2, acc2, 0, 0, 0);
      acc3 = __builtin_amdgcn_mfma_f32_32x32x16_f16(aL, bf3, acc3, 0, 0, 0);
    }
  }

#define ST_TILE(ACC, TT)                                                        \
  {                                                                             \
    const int r_o = wv * 2 + ((TT) >> 1);                                       \
    const int gx = x0 + ((TT) & 1) * 32 + l31;                                  \
    float* op = out + ((size_t)n * 32 + kb) * 65536 + (y0 + r_o) * 256 + gx;    \
    _Pragma("unroll")                                                           \
    for (int reg = 0; reg < 16; ++reg) {                                        \
      int krel = (reg & 3) + 8 * (reg >> 2);                                    \
      op[(size_t)krel * 65536] = ACC[reg];                                      \
    }                                                                           \
  }

  ST_TILE(acc0, 0)
  ST_TILE(acc1, 1)
  ST_TILE(acc2, 2)
  ST_TILE(acc3, 3)
#undef ST_TILE
}

extern "C" void kernel_launch(void* const* d_in, const int* in_sizes, int n_in,
                              void* d_out, int out_size, void* d_ws, size_t ws_size,
                              hipStream_t stream) {
  (void)in_sizes; (void)n_in; (void)out_size; (void)ws_size;
  const float* x     = (const float*)d_in[0];
  const float* w_bar = (const float*)d_in[1];
  const float* bias  = (const float*)d_in[2];
  float* out = (float*)d_out;
  unsigned short* wS = (unsigned short*)d_ws;  // 2*9216 ushort = 36864 B scratch

  sn_prep_kernel<<<1, 1024, 0, stream>>>(w_bar, wS);
  dim3 grid(256 / 64, 256 / 16, 32);  // (x-tiles, y-tiles, n)
  sn_conv_mfma<<<grid, 512, 0, stream>>>(x, wS, bias, out);
}